// Round 10
// baseline (211.155 us; speedup 1.0000x reference)
//
#include <hip/hip_runtime.h>

#define NN 50000
#define FIN 128
#define HC 256
#define NH 8
#define NE 800000
#define WROW 136        // padded LDS row (shorts); rows 16B-aligned
#define GEMMB 391       // 391*128 rows >= NN; each gemm block does all 4 column chunks
#define NBLK1 3516      // 391 gemm + 3125 fill (3125*256 == NE exactly)
#define OVFCAP 131072

typedef __attribute__((ext_vector_type(8))) short short8;
typedef __attribute__((ext_vector_type(4))) short short4v;
typedef __attribute__((ext_vector_type(4))) float floatx4;

__device__ __forceinline__ float bf2f(unsigned short u) {
    union { unsigned int i; float f; } v; v.i = ((unsigned int)u) << 16; return v.f;
}
__device__ __forceinline__ unsigned short f2bf(float f) {
    union { float f; unsigned int i; } v; v.f = f;
    unsigned int r = v.i + 0x7fffu + ((v.i >> 16) & 1u);
    return (unsigned short)(r >> 16);
}
__device__ __forceinline__ float lrelu(float x) { return x > 0.f ? x : 0.2f * x; }
__device__ __forceinline__ float ldf(const void* p, int f32, long long i) {
    return f32 ? ((const float*)p)[i] : bf2f(((const unsigned short*)p)[i]);
}
__device__ __forceinline__ float sel8(const float s[2][4], int t2, int rr) {
    float a0 = t2 ? s[1][0] : s[0][0];
    float a1 = t2 ? s[1][1] : s[0][1];
    float a2 = t2 ? s[1][2] : s[0][2];
    float a3 = t2 ? s[1][3] : s[0][3];
    return (rr == 0) ? a0 : ((rr == 1) ? a1 : ((rr == 2) ? a2 : a3));
}
// bf16 pair unpack from one dword: low short = <<16, high short = mask (no shift)
__device__ __forceinline__ float blo(unsigned int u) {
    union { unsigned int i; float f; } v; v.i = u << 16; return v.f;
}
__device__ __forceinline__ float bhi(unsigned int u) {
    union { unsigned int i; float f; } v; v.i = u & 0xFFFF0000u; return v.f;
}

// ---- K1: blocks < GEMMB: MFMA GEMM + attention scores. W staged in FOUR
//      64-column chunks -> LDS 17,408 B (was 34,816) -> ~7 blocks/CU (was 4).
//      The fill blocks share this kernel and its LDS allocation, so halving
//      LDS doubles the latency-bound fill waves resident per CU.
//      blocks >= GEMMB: bucket fill, 1 edge/thread, NT streaming, atomic early.
__global__ __launch_bounds__(256) void k_front(
        const void* __restrict__ x, const int* __restrict__ ei,
        const void* __restrict__ dpm, const void* __restrict__ W,
        const void* __restrict__ as_, const void* __restrict__ ad_,
        int* __restrict__ flags, unsigned short* __restrict__ h,
        float* __restrict__ a_src, float* __restrict__ a_dst,
        int* __restrict__ cnt, int* __restrict__ ovfcnt,
        unsigned int* __restrict__ bucket, int2* __restrict__ ovf,
        int cap, int capl2) {
    __shared__ unsigned short lwt[64 * WROW];   // 17,408 B
    __shared__ int s_bad, s_nz;
    const int tid = threadIdx.x;
    const int b = blockIdx.x;

    // dtype probe (local per block; leading words are L2-hot)
    if (tid == 0) { s_bad = 0; s_nz = 0; }
    __syncthreads();
    {
        unsigned int wv = ((const unsigned int*)dpm)[tid];   // fp32 dp_mask words: 0 or 2.5f
        if (wv != 0u && wv != 0x40200000u) atomicAdd(&s_bad, 1);
        if (((const unsigned int*)ei)[2 * tid + 1] != 0u) atomicAdd(&s_nz, 1);
    }
    __syncthreads();
    const int f32 = (s_bad == 0) ? 1 : 0;
    const int i64 = (s_nz == 0) ? 1 : 0;
    if (b == 0 && tid == 0) { flags[0] = f32; flags[1] = i64; }

    if (b < GEMMB) {
        const int lane = tid & 63;
        const int wave = tid >> 6;
        const int lrow = lane & 15;
        const int quad = lane >> 4;
        const int row0w = b * 128 + wave * 32;

        // ---- load x rows once (bf16 fragments in registers, reused by all chunks) ----
        short8 a[2][4];
        #pragma unroll
        for (int t = 0; t < 2; t++)
            #pragma unroll
            for (int q = 0; q < 4; q++)
                #pragma unroll
                for (int j = 0; j < 8; j++) a[t][q][j] = 0;

        #pragma unroll
        for (int t = 0; t < 2; t++) {
            int row = row0w + t * 16 + lrow;
            if (row < NN) {
                if (f32) {
                    const float* xp = (const float*)x + (long long)row * FIN + quad * 8;
                    #pragma unroll
                    for (int q = 0; q < 4; q++) {
                        floatx4 u0 = *(const floatx4*)(xp + q * 32);
                        floatx4 u1 = *(const floatx4*)(xp + q * 32 + 4);
                        #pragma unroll
                        for (int j = 0; j < 4; j++) {
                            a[t][q][j]     = (short)f2bf(u0[j]);
                            a[t][q][j + 4] = (short)f2bf(u1[j]);
                        }
                    }
                } else {
                    const unsigned short* xp = (const unsigned short*)x + (long long)row * FIN + quad * 8;
                    #pragma unroll
                    for (int q = 0; q < 4; q++) a[t][q] = *(const short8*)(xp + q * 32);
                }
            }
        }

        #pragma unroll
        for (int ch = 0; ch < 4; ch++) {
            if (ch) __syncthreads();       // all reads of previous chunk done
            // ---- stage W^T chunk (64 cols x 128 k): 4 threads/col, 32 k's each ----
            {
                const int lcol = tid & 63;
                const int col = ch * 64 + lcol;
                const int k0 = (tid >> 6) * 32;
                if (f32) {
                    const float* wp = (const float*)W + col;
                    for (int k = k0; k < k0 + 32; k++) lwt[lcol * WROW + k] = f2bf(wp[(long long)k * HC]);
                } else {
                    const unsigned short* wp = (const unsigned short*)W + col;
                    for (int k = k0; k < k0 + 32; k++) lwt[lcol * WROW + k] = wp[(long long)k * HC];
                }
            }
            __syncthreads();

            float sS[2][4], sD[2][4];
            #pragma unroll
            for (int ct = 0; ct < 4; ct++) {
                if ((ct & 1) == 0) {
                    #pragma unroll
                    for (int t = 0; t < 2; t++)
                        #pragma unroll
                        for (int r = 0; r < 4; r++) { sS[t][r] = 0.f; sD[t][r] = 0.f; }
                }
                floatx4 acc0 = {0.f, 0.f, 0.f, 0.f};
                floatx4 acc1 = {0.f, 0.f, 0.f, 0.f};
                const unsigned short* wp = lwt + (ct * 16 + lrow) * WROW + quad * 8;
                #pragma unroll
                for (int q = 0; q < 4; q++) {
                    short8 bb = *(const short8*)(wp + q * 32);
                    acc0 = __builtin_amdgcn_mfma_f32_16x16x32_bf16(a[0][q], bb, acc0, 0, 0, 0);
                    acc1 = __builtin_amdgcn_mfma_f32_16x16x32_bf16(a[1][q], bb, acc1, 0, 0, 0);
                }
                const int gcol = ch * 64 + ct * 16 + lrow;
                // C/D: col = lane&15, row = quad*4 + reg
                #pragma unroll
                for (int r = 0; r < 4; r++) {
                    int orow = row0w + quad * 4 + r;
                    if (orow < NN) h[(long long)orow * HC + gcol] = f2bf(acc0[r]);
                    int orow1 = orow + 16;
                    if (orow1 < NN) h[(long long)orow1 * HC + gcol] = f2bf(acc1[r]);
                }
                float tS = ldf(as_, f32, gcol);
                float tD = ldf(ad_, f32, gcol);
                #pragma unroll
                for (int r = 0; r < 4; r++) {
                    sS[0][r] += acc0[r] * tS;  sS[1][r] += acc1[r] * tS;
                    sD[0][r] += acc0[r] * tD;  sD[1][r] += acc1[r] * tD;
                }
                if (ct & 1) {   // head (ch*2 + ct>>1) complete: reduce over 16-lane col group
                    #pragma unroll
                    for (int m = 1; m <= 8; m <<= 1)
                        #pragma unroll
                        for (int t = 0; t < 2; t++)
                            #pragma unroll
                            for (int r = 0; r < 4; r++) {
                                sS[t][r] += __shfl_xor(sS[t][r], m);
                                sD[t][r] += __shfl_xor(sD[t][r], m);
                            }
                    int hd = ch * 2 + (ct >> 1);
                    if (lrow < 8) {
                        int t2 = lrow >> 2, rr = lrow & 3;
                        int row = row0w + t2 * 16 + quad * 4 + rr;
                        if (row < NN) a_src[row * NH + hd] = sel8(sS, t2, rr);
                    } else {
                        int lr = lrow - 8;
                        int t2 = lr >> 2, rr = lr & 3;
                        int row = row0w + t2 * 16 + quad * 4 + rr;
                        if (row < NN) a_dst[row * NH + hd] = sel8(sD, t2, rr);
                    }
                }
            }
        }
    } else {
        // ---- bucket fill: one edge per thread, NT streaming, atomic early ----
        const long long e = (long long)(b - GEMMB) * 256 + tid;   // < NE by construction
        int dst, src;
        if (i64) {
            dst = (int)__builtin_nontemporal_load((const long long*)ei + e);
            src = (int)__builtin_nontemporal_load((const long long*)ei + NE + e);
        } else {
            dst = __builtin_nontemporal_load(ei + e);
            src = __builtin_nontemporal_load(ei + NE + e);
        }
        int pos;
        unsigned int msk = 0;
        if (f32) {
            const floatx4* dp = (const floatx4*)((const float*)dpm + e * 8);
            floatx4 d0 = __builtin_nontemporal_load(dp);
            floatx4 d1 = __builtin_nontemporal_load(dp + 1);
            pos = atomicAdd(&cnt[dst], 1);         // in flight during mask VALU
            #pragma unroll
            for (int j = 0; j < 4; j++) {
                msk |= (d0[j] != 0.f ? 1u : 0u) << j;
                msk |= (d1[j] != 0.f ? 1u : 0u) << (4 + j);
            }
        } else {
            const short4v* dp = (const short4v*)((const unsigned short*)dpm + e * 8);
            short4v d0 = __builtin_nontemporal_load(dp);
            short4v d1 = __builtin_nontemporal_load(dp + 1);
            pos = atomicAdd(&cnt[dst], 1);
            #pragma unroll
            for (int j = 0; j < 4; j++) {
                msk |= (d0[j] != 0 ? 1u : 0u) << j;
                msk |= (d1[j] != 0 ? 1u : 0u) << (4 + j);
            }
        }
        unsigned int entry = (unsigned int)src | (msk << 16);
        if (pos < cap) {
            __builtin_nontemporal_store(entry, &bucket[((long long)dst << capl2) + pos]);
        } else {
            int op = atomicAdd(ovfcnt, 1);
            if (op < OVFCAP) ovf[op] = make_int2(dst, (int)entry);
        }
    }
}

// ---- K2 v6 (unchanged from R8; fetch-throughput-bound at ~2.76 TB/s on
//      ~160 MB of essential cross-XCD random h-gather traffic — frozen).
__global__ __launch_bounds__(256) void k_aggr(
        const int* __restrict__ cnt, const int* __restrict__ ovfcnt,
        const unsigned int* __restrict__ bucket, const int2* __restrict__ ovf,
        const float* __restrict__ a_src, const float* __restrict__ a_dst,
        const unsigned short* __restrict__ h, const void* __restrict__ dps,
        const int* __restrict__ flags, const void* __restrict__ bs_,
        void* __restrict__ out, int cap, int capl2) {
    __shared__ float wsh[4 * 2 * 8 * 68];      // 4 waves x 2 nodes x [8][68] = 17,408 B
    const int wid = blockIdx.x * 4 + (threadIdx.x >> 6);
    const int lane = threadIdx.x & 63;
    const int nA = wid * 2;
    if (nA >= NN) return;
    const int uA = __builtin_amdgcn_readfirstlane(nA);   // wave-uniform -> SGPR
    const int uB = uA + 1;                               // NN even -> uB < NN
    const int wave = threadIdx.x >> 6;
    const int f32 = flags[0];
    int novf = *ovfcnt; novf = novf > OVFCAP ? OVFCAP : novf;
    int mnA = cnt[uA]; mnA = mnA < cap ? mnA : cap;
    int mnB = cnt[uB]; mnB = mnB < cap ? mnB : cap;
    const unsigned int* __restrict__ bpA = bucket + ((long long)uA << capl2);
    const unsigned int* __restrict__ bpB = bucket + ((long long)uB << capl2);

    const int half = lane >> 5;            // 0 = produce for A, 1 = for B
    const int l32 = lane & 31;
    const int hh = lane >> 3;              // consumer head of this lane
    const int cb = lane * 4;               // channel base within h-row (shorts)

    const int mnH = half ? mnB : mnA;
    const int unH = half ? uB : uA;
    const unsigned int* __restrict__ bpH = half ? bpB : bpA;
    float* __restrict__ wl = wsh + wave * (2 * 8 * 68) + half * (8 * 68);

    // ---- producer pass 1: edge l32 (0..31) of own node ----
    int lc = l32 < mnH ? l32 : (mnH > 0 ? mnH - 1 : 0);
    unsigned int ue = bpH[lc];
    {
        int esrc = (int)(ue & 0xFFFFu);
        floatx4 as0 = *(const floatx4*)(a_src + esrc * NH);
        floatx4 as1 = *(const floatx4*)(a_src + esrc * NH + 4);
        floatx4 ad0 = *(const floatx4*)(a_dst + unH * NH);
        floatx4 ad1 = *(const floatx4*)(a_dst + unH * NH + 4);
        const bool valid = l32 < mnH;
        #pragma unroll
        for (int k = 0; k < 8; k++) {
            float al = (k < 4 ? as0[k & 3] : as1[k & 3]) + (k < 4 ? ad0[k & 3] : ad1[k & 3]);
            float w = __expf(fmaxf(al, 0.2f * al));
            w = valid ? w : 0.f;
            wl[k * 68 + l32] = ((ue >> (16 + k)) & 1u) ? w : -w;   // sign = dropout bit
        }
    }
    // ---- producer pass 2 (rare, wave-uniform): edges 32..63 ----
    unsigned int ue2 = 0u;
    if (mnA > 32 || mnB > 32) {
        int idx2 = 32 + l32;
        int lc2 = idx2 < mnH ? idx2 : (mnH > 0 ? mnH - 1 : 0);
        ue2 = bpH[lc2];
        int esrc = (int)(ue2 & 0xFFFFu);
        floatx4 as0 = *(const floatx4*)(a_src + esrc * NH);
        floatx4 as1 = *(const floatx4*)(a_src + esrc * NH + 4);
        floatx4 ad0 = *(const floatx4*)(a_dst + unH * NH);
        floatx4 ad1 = *(const floatx4*)(a_dst + unH * NH + 4);
        const bool valid = idx2 < mnH;
        #pragma unroll
        for (int k = 0; k < 8; k++) {
            float al = (k < 4 ? as0[k & 3] : as1[k & 3]) + (k < 4 ? ad0[k & 3] : ad1[k & 3]);
            float w = __expf(fmaxf(al, 0.2f * al));
            w = valid ? w : 0.f;
            wl[k * 68 + 32 + l32] = ((ue2 >> (16 + k)) & 1u) ? w : -w;
        }
    }
    __asm__ volatile("s_waitcnt lgkmcnt(0)" ::: "memory");   // wave-local LDS ready

    float dnA = 0.f, dnB = 0.f;
    float aA0 = 0.f, aA1 = 0.f, aA2 = 0.f, aA3 = 0.f;
    float aB0 = 0.f, aB1 = 0.f, aB2 = 0.f, aB3 = 0.f;
    const float* __restrict__ wrA = wsh + wave * (2 * 8 * 68) + hh * 68;
    const float* __restrict__ wrB = wrA + 8 * 68;

    // A edge j source holder: j<32 -> ue@lane j ; j>=32 -> ue2@lane j-32
    // B edge j source holder: j<32 -> ue@lane 32+j ; j>=32 -> ue2@lane j
    #pragma unroll
    for (int c = 0; c < 8; c++) {
        if (8 * c < mnA) {                 // wave-uniform scalar branch
            #define CONSA(K) { \
                float wv = wrA[8 * c + K]; \
                dnA += fabsf(wv); \
                int s = (c < 4 ? __builtin_amdgcn_readlane((int)ue, 8 * c + K) \
                               : __builtin_amdgcn_readlane((int)ue2, 8 * c + K - 32)) & 0xFFFF; \
                uint2 v = make_uint2(0u, 0u); \
                if (wv > 0.f) v = *(const uint2*)(h + ((long long)s << 8) + cb); \
                float p = wv * 2.5f; \
                aA0 = fmaf(p, blo(v.x), aA0); aA1 = fmaf(p, bhi(v.x), aA1); \
                aA2 = fmaf(p, blo(v.y), aA2); aA3 = fmaf(p, bhi(v.y), aA3); }
            CONSA(0) CONSA(1) CONSA(2) CONSA(3) CONSA(4) CONSA(5) CONSA(6) CONSA(7)
            #undef CONSA
        }
        if (8 * c < mnB) {
            #define CONSB(K) { \
                float wv = wrB[8 * c + K]; \
                dnB += fabsf(wv); \
                int s = (c < 4 ? __builtin_amdgcn_readlane((int)ue, 32 + 8 * c + K) \
                               : __builtin_amdgcn_readlane((int)ue2, 8 * c + K)) & 0xFFFF; \
                uint2 v = make_uint2(0u, 0u); \
                if (wv > 0.f) v = *(const uint2*)(h + ((long long)s << 8) + cb); \
                float p = wv * 2.5f; \
                aB0 = fmaf(p, blo(v.x), aB0); aB1 = fmaf(p, bhi(v.x), aB1); \
                aB2 = fmaf(p, blo(v.y), aB2); aB3 = fmaf(p, bhi(v.y), aB3); }
            CONSB(0) CONSB(1) CONSB(2) CONSB(3) CONSB(4) CONSB(5) CONSB(6) CONSB(7)
            #undef CONSB
        }
    }

    // overflow sweep (novf ~ 0 in practice; correct for any value)
    for (int i = 0; i < novf; i++) {
        int2 tv = ovf[i];
        if (tv.x == uA || tv.x == uB) {
            unsigned int u = (unsigned int)tv.y;
            int src = (int)(u & 0xFFFFu);
            float adh = a_dst[tv.x * NH + hh];
            float w = __expf(lrelu(a_src[src * NH + hh] + adh));
            uint2 hv = make_uint2(0u, 0u);
            if ((u >> (16 + hh)) & 1u) hv = *(const uint2*)(h + ((long long)src << 8) + cb);
            float p = w * 2.5f;
            if (tv.x == uA) {
                dnA += w;
                aA0 = fmaf(p, blo(hv.x), aA0); aA1 = fmaf(p, bhi(hv.x), aA1);
                aA2 = fmaf(p, blo(hv.y), aA2); aA3 = fmaf(p, bhi(hv.y), aA3);
            } else {
                dnB += w;
                aB0 = fmaf(p, blo(hv.x), aB0); aB1 = fmaf(p, bhi(hv.x), aB1);
                aB2 = fmaf(p, blo(hv.y), aB2); aB3 = fmaf(p, bhi(hv.y), aB3);
            }
        }
    }
    { // self-loops, both nodes
        float adhA = a_dst[uA * NH + hh], adhB = a_dst[uB * NH + hh];
        float wSA = __expf(lrelu(a_src[uA * NH + hh] + adhA));
        float wSB = __expf(lrelu(a_src[uB * NH + hh] + adhB));
        dnA += wSA; dnB += wSB;
        float pSA = wSA * ldf(dps, f32, (long long)uA * NH + hh);
        float pSB = wSB * ldf(dps, f32, (long long)uB * NH + hh);
        uint2 hvA = *(const uint2*)(h + ((long long)uA << 8) + cb);
        uint2 hvB = *(const uint2*)(h + ((long long)uB << 8) + cb);
        aA0 = fmaf(pSA, blo(hvA.x), aA0); aA1 = fmaf(pSA, bhi(hvA.x), aA1);
        aA2 = fmaf(pSA, blo(hvA.y), aA2); aA3 = fmaf(pSA, bhi(hvA.y), aA3);
        aB0 = fmaf(pSB, blo(hvB.x), aB0); aB1 = fmaf(pSB, bhi(hvB.x), aB1);
        aB2 = fmaf(pSB, blo(hvB.y), aB2); aB3 = fmaf(pSB, bhi(hvB.y), aB3);
    }
    float invA = 1.0f / dnA, invB = 1.0f / dnB;
    float b0 = ldf(bs_, f32, cb + 0), b1 = ldf(bs_, f32, cb + 1);
    float b2 = ldf(bs_, f32, cb + 2), b3 = ldf(bs_, f32, cb + 3);
    if (f32) {
        floatx4 oA = {aA0 * invA + b0, aA1 * invA + b1, aA2 * invA + b2, aA3 * invA + b3};
        floatx4 oB = {aB0 * invB + b0, aB1 * invB + b1, aB2 * invB + b2, aB3 * invB + b3};
        *(floatx4*)((float*)out + (long long)uA * HC + cb) = oA;
        *(floatx4*)((float*)out + (long long)uB * HC + cb) = oB;
    } else {
        short4v oA, oB;
        oA[0] = (short)f2bf(aA0 * invA + b0); oA[1] = (short)f2bf(aA1 * invA + b1);
        oA[2] = (short)f2bf(aA2 * invA + b2); oA[3] = (short)f2bf(aA3 * invA + b3);
        oB[0] = (short)f2bf(aB0 * invB + b0); oB[1] = (short)f2bf(aB1 * invB + b1);
        oB[2] = (short)f2bf(aB2 * invB + b2); oB[3] = (short)f2bf(aB3 * invB + b3);
        *(short4v*)((unsigned short*)out + (long long)uA * HC + cb) = oA;
        *(short4v*)((unsigned short*)out + (long long)uB * HC + cb) = oB;
    }
}

extern "C" void kernel_launch(void* const* d_in, const int* in_sizes, int n_in,
                              void* d_out, int out_size, void* d_ws, size_t ws_size,
                              hipStream_t stream) {
    const void* x       = d_in[0];
    const int*  ei      = (const int*)d_in[1];
    const void* dp_mask = d_in[2];
    const void* dp_self = d_in[3];
    const void* W       = d_in[4];
    const void* att_s   = d_in[5];
    const void* att_d   = d_in[6];
    const void* bias    = d_in[7];

    char* w = (char*)d_ws;
    unsigned short* h      = (unsigned short*)(w + 0);             // 25,600,000
    float*          a_src  = (float*)(w + 25600000);               //  1,600,000
    float*          a_dst  = (float*)(w + 27200000);               //  1,600,000
    int*            cnt    = (int*)(w + 28800000);                 //    200,000
    int*            ovfcnt = (int*)(w + 29000000);                 //          4
    int*            flags  = (int*)(w + 29000064);                 //          8
    int2*           ovf    = (int2*)(w + 29000960);                //  1,048,576
    unsigned int*   bucket = (unsigned int*)(w + 30049536);        //  cap*200,000

    // 512 B slack after bucket region (clamped reads stay in-row; margin only)
    long long avail = (long long)ws_size - 30049536LL - 512LL;
    int cap = 64, capl2 = 6;
    while (cap > 4 && (long long)cap * 200000LL > avail) { cap >>= 1; capl2--; }

    // zero cnt + ovfcnt (+flags; flags rewritten by k_front before k_aggr reads)
    hipMemsetAsync(cnt, 0, 200960, stream);
    k_front<<<NBLK1, 256, 0, stream>>>(x, ei, dp_mask, W, att_s, att_d,
                                       flags, h, a_src, a_dst, cnt, ovfcnt, bucket, ovf,
                                       cap, capl2);
    k_aggr<<<NN / 8, 256, 0, stream>>>(cnt, ovfcnt, bucket, ovf, a_src, a_dst, h,
                                       dp_self, flags, bias, d_out, cap, capl2);
}

// Round 11
// 201.007 us; speedup vs baseline: 1.0505x; 1.0505x over previous
//
#include <hip/hip_runtime.h>

#define NN 50000
#define FIN 128
#define HC 256
#define NH 8
#define NE 800000
#define WROW 136        // padded LDS row (shorts); rows 16B-aligned
#define GEMMB 391       // 391*128 rows >= NN; each gemm block does BOTH column halves
#define NBLK1 3516      // 391 gemm + 3125 fill (3125*256 == NE exactly)
#define OVFCAP 131072

typedef __attribute__((ext_vector_type(8))) short short8;
typedef __attribute__((ext_vector_type(4))) short short4v;
typedef __attribute__((ext_vector_type(4))) float floatx4;

__device__ __forceinline__ float bf2f(unsigned short u) {
    union { unsigned int i; float f; } v; v.i = ((unsigned int)u) << 16; return v.f;
}
__device__ __forceinline__ unsigned short f2bf(float f) {
    union { float f; unsigned int i; } v; v.f = f;
    unsigned int r = v.i + 0x7fffu + ((v.i >> 16) & 1u);
    return (unsigned short)(r >> 16);
}
__device__ __forceinline__ float lrelu(float x) { return x > 0.f ? x : 0.2f * x; }
__device__ __forceinline__ float ldf(const void* p, int f32, long long i) {
    return f32 ? ((const float*)p)[i] : bf2f(((const unsigned short*)p)[i]);
}
__device__ __forceinline__ float sel8(const float s[2][4], int t2, int rr) {
    float a0 = t2 ? s[1][0] : s[0][0];
    float a1 = t2 ? s[1][1] : s[0][1];
    float a2 = t2 ? s[1][2] : s[0][2];
    float a3 = t2 ? s[1][3] : s[0][3];
    return (rr == 0) ? a0 : ((rr == 1) ? a1 : ((rr == 2) ? a2 : a3));
}
// bf16 pair unpack from one dword: low short = <<16, high short = mask (no shift)
__device__ __forceinline__ float blo(unsigned int u) {
    union { unsigned int i; float f; } v; v.i = u << 16; return v.f;
}
__device__ __forceinline__ float bhi(unsigned int u) {
    union { unsigned int i; float f; } v; v.i = u & 0xFFFF0000u; return v.f;
}

// ---- K1 (R8-proven best config): blocks < GEMMB: MFMA GEMM + attention
//      scores — x loaded ONCE into registers, W staged per 128-col half into a
//      34,816 B LDS buffer (4 blocks/CU), two sequential halves.
//      blocks >= GEMMB: bucket fill, 1 edge/thread, NT streaming, atomic early.
//      (R10's 4x64-col chunking regressed: occupancy is NOT LDS-capped; the
//      fill path is atomic-throughput-bound.)
__global__ __launch_bounds__(256) void k_front(
        const void* __restrict__ x, const int* __restrict__ ei,
        const void* __restrict__ dpm, const void* __restrict__ W,
        const void* __restrict__ as_, const void* __restrict__ ad_,
        int* __restrict__ flags, unsigned short* __restrict__ h,
        float* __restrict__ a_src, float* __restrict__ a_dst,
        int* __restrict__ cnt, int* __restrict__ ovfcnt,
        unsigned int* __restrict__ bucket, int2* __restrict__ ovf,
        int cap, int capl2) {
    __shared__ unsigned short lwt[128 * WROW];   // 34,816 B
    __shared__ int s_bad, s_nz;
    const int tid = threadIdx.x;
    const int b = blockIdx.x;

    // dtype probe (local per block; leading words are L2-hot)
    if (tid == 0) { s_bad = 0; s_nz = 0; }
    __syncthreads();
    {
        unsigned int wv = ((const unsigned int*)dpm)[tid];   // fp32 dp_mask words: 0 or 2.5f
        if (wv != 0u && wv != 0x40200000u) atomicAdd(&s_bad, 1);
        if (((const unsigned int*)ei)[2 * tid + 1] != 0u) atomicAdd(&s_nz, 1);
    }
    __syncthreads();
    const int f32 = (s_bad == 0) ? 1 : 0;
    const int i64 = (s_nz == 0) ? 1 : 0;
    if (b == 0 && tid == 0) { flags[0] = f32; flags[1] = i64; }

    if (b < GEMMB) {
        const int lane = tid & 63;
        const int wave = tid >> 6;
        const int lrow = lane & 15;
        const int quad = lane >> 4;
        const int row0w = b * 128 + wave * 32;

        // ---- load x rows once (bf16 fragments in registers for both halves) ----
        short8 a[2][4];
        #pragma unroll
        for (int t = 0; t < 2; t++)
            #pragma unroll
            for (int q = 0; q < 4; q++)
                #pragma unroll
                for (int j = 0; j < 8; j++) a[t][q][j] = 0;

        #pragma unroll
        for (int t = 0; t < 2; t++) {
            int row = row0w + t * 16 + lrow;
            if (row < NN) {
                if (f32) {
                    const float* xp = (const float*)x + (long long)row * FIN + quad * 8;
                    #pragma unroll
                    for (int q = 0; q < 4; q++) {
                        floatx4 u0 = *(const floatx4*)(xp + q * 32);
                        floatx4 u1 = *(const floatx4*)(xp + q * 32 + 4);
                        #pragma unroll
                        for (int j = 0; j < 4; j++) {
                            a[t][q][j]     = (short)f2bf(u0[j]);
                            a[t][q][j + 4] = (short)f2bf(u1[j]);
                        }
                    }
                } else {
                    const unsigned short* xp = (const unsigned short*)x + (long long)row * FIN + quad * 8;
                    #pragma unroll
                    for (int q = 0; q < 4; q++) a[t][q] = *(const short8*)(xp + q * 32);
                }
            }
        }

        #pragma unroll
        for (int ch = 0; ch < 2; ch++) {
            if (ch) __syncthreads();       // all reads of previous half done
            // ---- stage W^T half: two threads per column, 64 k's each; coalesced ----
            {
                const int lcol = tid & 127;
                const int col = ch * 128 + lcol;
                const int k0 = (tid >> 7) * 64;
                if (f32) {
                    const float* wp = (const float*)W + col;
                    for (int k = k0; k < k0 + 64; k++) lwt[lcol * WROW + k] = f2bf(wp[(long long)k * HC]);
                } else {
                    const unsigned short* wp = (const unsigned short*)W + col;
                    for (int k = k0; k < k0 + 64; k++) lwt[lcol * WROW + k] = wp[(long long)k * HC];
                }
            }
            __syncthreads();

            float sS[2][4], sD[2][4];
            #pragma unroll 4
            for (int ct = 0; ct < 8; ct++) {
                if ((ct & 1) == 0) {
                    #pragma unroll
                    for (int t = 0; t < 2; t++)
                        #pragma unroll
                        for (int r = 0; r < 4; r++) { sS[t][r] = 0.f; sD[t][r] = 0.f; }
                }
                floatx4 acc0 = {0.f, 0.f, 0.f, 0.f};
                floatx4 acc1 = {0.f, 0.f, 0.f, 0.f};
                const unsigned short* wp = lwt + (ct * 16 + lrow) * WROW + quad * 8;
                #pragma unroll
                for (int q = 0; q < 4; q++) {
                    short8 bb = *(const short8*)(wp + q * 32);
                    acc0 = __builtin_amdgcn_mfma_f32_16x16x32_bf16(a[0][q], bb, acc0, 0, 0, 0);
                    acc1 = __builtin_amdgcn_mfma_f32_16x16x32_bf16(a[1][q], bb, acc1, 0, 0, 0);
                }
                const int gcol = ch * 128 + ct * 16 + lrow;
                // C/D: col = lane&15, row = quad*4 + reg
                #pragma unroll
                for (int r = 0; r < 4; r++) {
                    int orow = row0w + quad * 4 + r;
                    if (orow < NN) h[(long long)orow * HC + gcol] = f2bf(acc0[r]);
                    int orow1 = orow + 16;
                    if (orow1 < NN) h[(long long)orow1 * HC + gcol] = f2bf(acc1[r]);
                }
                float tS = ldf(as_, f32, gcol);
                float tD = ldf(ad_, f32, gcol);
                #pragma unroll
                for (int r = 0; r < 4; r++) {
                    sS[0][r] += acc0[r] * tS;  sS[1][r] += acc1[r] * tS;
                    sD[0][r] += acc0[r] * tD;  sD[1][r] += acc1[r] * tD;
                }
                if (ct & 1) {   // head (ch*4 + ct>>1) complete: reduce over 16-lane col group
                    #pragma unroll
                    for (int m = 1; m <= 8; m <<= 1)
                        #pragma unroll
                        for (int t = 0; t < 2; t++)
                            #pragma unroll
                            for (int r = 0; r < 4; r++) {
                                sS[t][r] += __shfl_xor(sS[t][r], m);
                                sD[t][r] += __shfl_xor(sD[t][r], m);
                            }
                    int hd = ch * 4 + (ct >> 1);
                    if (lrow < 8) {
                        int t2 = lrow >> 2, rr = lrow & 3;
                        int row = row0w + t2 * 16 + quad * 4 + rr;
                        if (row < NN) a_src[row * NH + hd] = sel8(sS, t2, rr);
                    } else {
                        int lr = lrow - 8;
                        int t2 = lr >> 2, rr = lr & 3;
                        int row = row0w + t2 * 16 + quad * 4 + rr;
                        if (row < NN) a_dst[row * NH + hd] = sel8(sD, t2, rr);
                    }
                }
            }
        }
    } else {
        // ---- bucket fill: one edge per thread, NT streaming, atomic early ----
        const long long e = (long long)(b - GEMMB) * 256 + tid;   // < NE by construction
        int dst, src;
        if (i64) {
            dst = (int)__builtin_nontemporal_load((const long long*)ei + e);
            src = (int)__builtin_nontemporal_load((const long long*)ei + NE + e);
        } else {
            dst = __builtin_nontemporal_load(ei + e);
            src = __builtin_nontemporal_load(ei + NE + e);
        }
        int pos;
        unsigned int msk = 0;
        if (f32) {
            const floatx4* dp = (const floatx4*)((const float*)dpm + e * 8);
            floatx4 d0 = __builtin_nontemporal_load(dp);
            floatx4 d1 = __builtin_nontemporal_load(dp + 1);
            pos = atomicAdd(&cnt[dst], 1);         // in flight during mask VALU
            #pragma unroll
            for (int j = 0; j < 4; j++) {
                msk |= (d0[j] != 0.f ? 1u : 0u) << j;
                msk |= (d1[j] != 0.f ? 1u : 0u) << (4 + j);
            }
        } else {
            const short4v* dp = (const short4v*)((const unsigned short*)dpm + e * 8);
            short4v d0 = __builtin_nontemporal_load(dp);
            short4v d1 = __builtin_nontemporal_load(dp + 1);
            pos = atomicAdd(&cnt[dst], 1);
            #pragma unroll
            for (int j = 0; j < 4; j++) {
                msk |= (d0[j] != 0 ? 1u : 0u) << j;
                msk |= (d1[j] != 0 ? 1u : 0u) << (4 + j);
            }
        }
        unsigned int entry = (unsigned int)src | (msk << 16);
        if (pos < cap) {
            __builtin_nontemporal_store(entry, &bucket[((long long)dst << capl2) + pos]);
        } else {
            int op = atomicAdd(ovfcnt, 1);
            if (op < OVFCAP) ovf[op] = make_int2(dst, (int)entry);
        }
    }
}

// ---- K2 v6 (R8-proven; fetch-throughput-bound at ~2.76 TB/s on ~160 MB of
//      essential random h-gather traffic: kept (edge,head) pairs x 64 B line.
//      Four structural variants converged to this rate — frozen).
__global__ __launch_bounds__(256) void k_aggr(
        const int* __restrict__ cnt, const int* __restrict__ ovfcnt,
        const unsigned int* __restrict__ bucket, const int2* __restrict__ ovf,
        const float* __restrict__ a_src, const float* __restrict__ a_dst,
        const unsigned short* __restrict__ h, const void* __restrict__ dps,
        const int* __restrict__ flags, const void* __restrict__ bs_,
        void* __restrict__ out, int cap, int capl2) {
    __shared__ float wsh[4 * 2 * 8 * 68];      // 4 waves x 2 nodes x [8][68] = 17,408 B
    const int wid = blockIdx.x * 4 + (threadIdx.x >> 6);
    const int lane = threadIdx.x & 63;
    const int nA = wid * 2;
    if (nA >= NN) return;
    const int uA = __builtin_amdgcn_readfirstlane(nA);   // wave-uniform -> SGPR
    const int uB = uA + 1;                               // NN even -> uB < NN
    const int wave = threadIdx.x >> 6;
    const int f32 = flags[0];
    int novf = *ovfcnt; novf = novf > OVFCAP ? OVFCAP : novf;
    int mnA = cnt[uA]; mnA = mnA < cap ? mnA : cap;
    int mnB = cnt[uB]; mnB = mnB < cap ? mnB : cap;
    const unsigned int* __restrict__ bpA = bucket + ((long long)uA << capl2);
    const unsigned int* __restrict__ bpB = bucket + ((long long)uB << capl2);

    const int half = lane >> 5;            // 0 = produce for A, 1 = for B
    const int l32 = lane & 31;
    const int hh = lane >> 3;              // consumer head of this lane
    const int cb = lane * 4;               // channel base within h-row (shorts)

    const int mnH = half ? mnB : mnA;
    const int unH = half ? uB : uA;
    const unsigned int* __restrict__ bpH = half ? bpB : bpA;
    float* __restrict__ wl = wsh + wave * (2 * 8 * 68) + half * (8 * 68);

    // ---- producer pass 1: edge l32 (0..31) of own node ----
    int lc = l32 < mnH ? l32 : (mnH > 0 ? mnH - 1 : 0);
    unsigned int ue = bpH[lc];
    {
        int esrc = (int)(ue & 0xFFFFu);
        floatx4 as0 = *(const floatx4*)(a_src + esrc * NH);
        floatx4 as1 = *(const floatx4*)(a_src + esrc * NH + 4);
        floatx4 ad0 = *(const floatx4*)(a_dst + unH * NH);
        floatx4 ad1 = *(const floatx4*)(a_dst + unH * NH + 4);
        const bool valid = l32 < mnH;
        #pragma unroll
        for (int k = 0; k < 8; k++) {
            float al = (k < 4 ? as0[k & 3] : as1[k & 3]) + (k < 4 ? ad0[k & 3] : ad1[k & 3]);
            float w = __expf(fmaxf(al, 0.2f * al));
            w = valid ? w : 0.f;
            wl[k * 68 + l32] = ((ue >> (16 + k)) & 1u) ? w : -w;   // sign = dropout bit
        }
    }
    // ---- producer pass 2 (rare, wave-uniform): edges 32..63 ----
    unsigned int ue2 = 0u;
    if (mnA > 32 || mnB > 32) {
        int idx2 = 32 + l32;
        int lc2 = idx2 < mnH ? idx2 : (mnH > 0 ? mnH - 1 : 0);
        ue2 = bpH[lc2];
        int esrc = (int)(ue2 & 0xFFFFu);
        floatx4 as0 = *(const floatx4*)(a_src + esrc * NH);
        floatx4 as1 = *(const floatx4*)(a_src + esrc * NH + 4);
        floatx4 ad0 = *(const floatx4*)(a_dst + unH * NH);
        floatx4 ad1 = *(const floatx4*)(a_dst + unH * NH + 4);
        const bool valid = idx2 < mnH;
        #pragma unroll
        for (int k = 0; k < 8; k++) {
            float al = (k < 4 ? as0[k & 3] : as1[k & 3]) + (k < 4 ? ad0[k & 3] : ad1[k & 3]);
            float w = __expf(fmaxf(al, 0.2f * al));
            w = valid ? w : 0.f;
            wl[k * 68 + 32 + l32] = ((ue2 >> (16 + k)) & 1u) ? w : -w;
        }
    }
    __asm__ volatile("s_waitcnt lgkmcnt(0)" ::: "memory");   // wave-local LDS ready

    float dnA = 0.f, dnB = 0.f;
    float aA0 = 0.f, aA1 = 0.f, aA2 = 0.f, aA3 = 0.f;
    float aB0 = 0.f, aB1 = 0.f, aB2 = 0.f, aB3 = 0.f;
    const float* __restrict__ wrA = wsh + wave * (2 * 8 * 68) + hh * 68;
    const float* __restrict__ wrB = wrA + 8 * 68;

    // A edge j source holder: j<32 -> ue@lane j ; j>=32 -> ue2@lane j-32
    // B edge j source holder: j<32 -> ue@lane 32+j ; j>=32 -> ue2@lane j
    #pragma unroll
    for (int c = 0; c < 8; c++) {
        if (8 * c < mnA) {                 // wave-uniform scalar branch
            #define CONSA(K) { \
                float wv = wrA[8 * c + K]; \
                dnA += fabsf(wv); \
                int s = (c < 4 ? __builtin_amdgcn_readlane((int)ue, 8 * c + K) \
                               : __builtin_amdgcn_readlane((int)ue2, 8 * c + K - 32)) & 0xFFFF; \
                uint2 v = make_uint2(0u, 0u); \
                if (wv > 0.f) v = *(const uint2*)(h + ((long long)s << 8) + cb); \
                float p = wv * 2.5f; \
                aA0 = fmaf(p, blo(v.x), aA0); aA1 = fmaf(p, bhi(v.x), aA1); \
                aA2 = fmaf(p, blo(v.y), aA2); aA3 = fmaf(p, bhi(v.y), aA3); }
            CONSA(0) CONSA(1) CONSA(2) CONSA(3) CONSA(4) CONSA(5) CONSA(6) CONSA(7)
            #undef CONSA
        }
        if (8 * c < mnB) {
            #define CONSB(K) { \
                float wv = wrB[8 * c + K]; \
                dnB += fabsf(wv); \
                int s = (c < 4 ? __builtin_amdgcn_readlane((int)ue, 32 + 8 * c + K) \
                               : __builtin_amdgcn_readlane((int)ue2, 8 * c + K)) & 0xFFFF; \
                uint2 v = make_uint2(0u, 0u); \
                if (wv > 0.f) v = *(const uint2*)(h + ((long long)s << 8) + cb); \
                float p = wv * 2.5f; \
                aB0 = fmaf(p, blo(v.x), aB0); aB1 = fmaf(p, bhi(v.x), aB1); \
                aB2 = fmaf(p, blo(v.y), aB2); aB3 = fmaf(p, bhi(v.y), aB3); }
            CONSB(0) CONSB(1) CONSB(2) CONSB(3) CONSB(4) CONSB(5) CONSB(6) CONSB(7)
            #undef CONSB
        }
    }

    // overflow sweep (novf ~ 0 in practice; correct for any value)
    for (int i = 0; i < novf; i++) {
        int2 tv = ovf[i];
        if (tv.x == uA || tv.x == uB) {
            unsigned int u = (unsigned int)tv.y;
            int src = (int)(u & 0xFFFFu);
            float adh = a_dst[tv.x * NH + hh];
            float w = __expf(lrelu(a_src[src * NH + hh] + adh));
            uint2 hv = make_uint2(0u, 0u);
            if ((u >> (16 + hh)) & 1u) hv = *(const uint2*)(h + ((long long)src << 8) + cb);
            float p = w * 2.5f;
            if (tv.x == uA) {
                dnA += w;
                aA0 = fmaf(p, blo(hv.x), aA0); aA1 = fmaf(p, bhi(hv.x), aA1);
                aA2 = fmaf(p, blo(hv.y), aA2); aA3 = fmaf(p, bhi(hv.y), aA3);
            } else {
                dnB += w;
                aB0 = fmaf(p, blo(hv.x), aB0); aB1 = fmaf(p, bhi(hv.x), aB1);
                aB2 = fmaf(p, blo(hv.y), aB2); aB3 = fmaf(p, bhi(hv.y), aB3);
            }
        }
    }
    { // self-loops, both nodes
        float adhA = a_dst[uA * NH + hh], adhB = a_dst[uB * NH + hh];
        float wSA = __expf(lrelu(a_src[uA * NH + hh] + adhA));
        float wSB = __expf(lrelu(a_src[uB * NH + hh] + adhB));
        dnA += wSA; dnB += wSB;
        float pSA = wSA * ldf(dps, f32, (long long)uA * NH + hh);
        float pSB = wSB * ldf(dps, f32, (long long)uB * NH + hh);
        uint2 hvA = *(const uint2*)(h + ((long long)uA << 8) + cb);
        uint2 hvB = *(const uint2*)(h + ((long long)uB << 8) + cb);
        aA0 = fmaf(pSA, blo(hvA.x), aA0); aA1 = fmaf(pSA, bhi(hvA.x), aA1);
        aA2 = fmaf(pSA, blo(hvA.y), aA2); aA3 = fmaf(pSA, bhi(hvA.y), aA3);
        aB0 = fmaf(pSB, blo(hvB.x), aB0); aB1 = fmaf(pSB, bhi(hvB.x), aB1);
        aB2 = fmaf(pSB, blo(hvB.y), aB2); aB3 = fmaf(pSB, bhi(hvB.y), aB3);
    }
    float invA = 1.0f / dnA, invB = 1.0f / dnB;
    float b0 = ldf(bs_, f32, cb + 0), b1 = ldf(bs_, f32, cb + 1);
    float b2 = ldf(bs_, f32, cb + 2), b3 = ldf(bs_, f32, cb + 3);
    if (f32) {
        floatx4 oA = {aA0 * invA + b0, aA1 * invA + b1, aA2 * invA + b2, aA3 * invA + b3};
        floatx4 oB = {aB0 * invB + b0, aB1 * invB + b1, aB2 * invB + b2, aB3 * invB + b3};
        *(floatx4*)((float*)out + (long long)uA * HC + cb) = oA;
        *(floatx4*)((float*)out + (long long)uB * HC + cb) = oB;
    } else {
        short4v oA, oB;
        oA[0] = (short)f2bf(aA0 * invA + b0); oA[1] = (short)f2bf(aA1 * invA + b1);
        oA[2] = (short)f2bf(aA2 * invA + b2); oA[3] = (short)f2bf(aA3 * invA + b3);
        oB[0] = (short)f2bf(aB0 * invB + b0); oB[1] = (short)f2bf(aB1 * invB + b1);
        oB[2] = (short)f2bf(aB2 * invB + b2); oB[3] = (short)f2bf(aB3 * invB + b3);
        *(short4v*)((unsigned short*)out + (long long)uA * HC + cb) = oA;
        *(short4v*)((unsigned short*)out + (long long)uB * HC + cb) = oB;
    }
}

extern "C" void kernel_launch(void* const* d_in, const int* in_sizes, int n_in,
                              void* d_out, int out_size, void* d_ws, size_t ws_size,
                              hipStream_t stream) {
    const void* x       = d_in[0];
    const int*  ei      = (const int*)d_in[1];
    const void* dp_mask = d_in[2];
    const void* dp_self = d_in[3];
    const void* W       = d_in[4];
    const void* att_s   = d_in[5];
    const void* att_d   = d_in[6];
    const void* bias    = d_in[7];

    char* w = (char*)d_ws;
    unsigned short* h      = (unsigned short*)(w + 0);             // 25,600,000
    float*          a_src  = (float*)(w + 25600000);               //  1,600,000
    float*          a_dst  = (float*)(w + 27200000);               //  1,600,000
    int*            cnt    = (int*)(w + 28800000);                 //    200,000
    int*            ovfcnt = (int*)(w + 29000000);                 //          4
    int*            flags  = (int*)(w + 29000064);                 //          8
    int2*           ovf    = (int2*)(w + 29000960);                //  1,048,576
    unsigned int*   bucket = (unsigned int*)(w + 30049536);        //  cap*200,000

    // 512 B slack after bucket region (clamped reads stay in-row; margin only)
    long long avail = (long long)ws_size - 30049536LL - 512LL;
    int cap = 64, capl2 = 6;
    while (cap > 4 && (long long)cap * 200000LL > avail) { cap >>= 1; capl2--; }

    // zero cnt + ovfcnt (+flags; flags rewritten by k_front before k_aggr reads)
    hipMemsetAsync(cnt, 0, 200960, stream);
    k_front<<<NBLK1, 256, 0, stream>>>(x, ei, dp_mask, W, att_s, att_d,
                                       flags, h, a_src, a_dst, cnt, ovfcnt, bucket, ovf,
                                       cap, capl2);
    k_aggr<<<NN / 8, 256, 0, stream>>>(cnt, ovfcnt, bucket, ovf, a_src, a_dst, h,
                                       dp_self, flags, bias, d_out, cap, capl2);
}